// Round 16
// baseline (483.955 us; speedup 1.0000x reference)
//
#include <hip/hip_runtime.h>
#include <hip/hip_bf16.h>

#define BATCH 4
#define SEQ   4096
#define LSEQ  512
#define DMODEL 1024
#define DFF_  4096
#define NHEAD 16
#define DK_   64
#define NSPLIT 8
#define FFSK  4

typedef __attribute__((ext_vector_type(4))) float f32x4;
typedef __attribute__((ext_vector_type(8))) __bf16 bf16x8;
typedef __attribute__((ext_vector_type(8))) unsigned short ushort8v;
typedef unsigned short u16;

__device__ __forceinline__ u16 f2bf(float f) {
  union { float f; unsigned int u; } c; c.f = f;
  unsigned int u = c.u;
  u += 0x7fffu + ((u >> 16) & 1u);
  return (u16)(u >> 16);
}
__device__ __forceinline__ float bf2f(u16 h) {
  union { unsigned int u; float f; } c; c.u = ((unsigned int)h) << 16;
  return c.f;
}
__device__ __forceinline__ void gload16(const void* g, void* l) {
  __builtin_amdgcn_global_load_lds(
      (const __attribute__((address_space(1))) unsigned int*)g,
      (__attribute__((address_space(3))) unsigned int*)l, 16, 0, 0);
}

// ---------------- LayerNorm (ddof=1) -> bf16, float4-vectorized ----------------
__global__ __launch_bounds__(256) void ln_kernel(
    const float* __restrict__ x, const float* __restrict__ alpha,
    const float* __restrict__ beta, u16* __restrict__ y)
{
  const int row = blockIdx.x;
  const int t = threadIdx.x;
  const float4 v = ((const float4*)(x + (size_t)row * DMODEL))[t];
  float s = v.x + v.y + v.z + v.w;
  float ss = v.x * v.x + v.y * v.y + v.z * v.z + v.w * v.w;
  for (int off = 32; off >= 1; off >>= 1) {
    s += __shfl_xor(s, off);
    ss += __shfl_xor(ss, off);
  }
  __shared__ float sbuf[4], ssbuf[4];
  int w = t >> 6;
  if ((t & 63) == 0) { sbuf[w] = s; ssbuf[w] = ss; }
  __syncthreads();
  s = sbuf[0] + sbuf[1] + sbuf[2] + sbuf[3];
  ss = ssbuf[0] + ssbuf[1] + ssbuf[2] + ssbuf[3];
  float mean = s * (1.f / DMODEL);
  float var = (ss - mean * mean * DMODEL) * (1.f / (DMODEL - 1));
  var = fmaxf(var, 0.f);
  float inv = 1.f / (sqrtf(var) + 1e-6f);
  const float4 a = ((const float4*)alpha)[t];
  const float4 bb = ((const float4*)beta)[t];
  ushort4 o;
  o.x = f2bf(a.x * (v.x - mean) * inv + bb.x);
  o.y = f2bf(a.y * (v.y - mean) * inv + bb.y);
  o.z = f2bf(a.z * (v.z - mean) * inv + bb.z);
  o.w = f2bf(a.w * (v.w - mean) * inv + bb.w);
  ((ushort4*)(y + (size_t)row * DMODEL))[t] = o;
}

// ---------------- batched transpose-convert: all 10 weights in ONE launch ----------------
__global__ __launch_bounds__(256) void wconv_all_kernel(
    const float* w0, const float* w1, const float* w2, const float* w3,
    const float* w4, const float* w5, const float* w6, const float* w7,
    const float* w8, const float* w9,
    u16* d0, u16* d1, u16* d2, u16* d3, u16* d4,
    u16* d5, u16* d6, u16* d7, u16* d8, u16* d9)
{
  const int z = blockIdx.z;
  const float* W; u16* Wt; int K, N;
  int bx = blockIdx.x, by = blockIdx.y;
  if (z < 8) {
    const float* ws[8] = {w0, w1, w2, w3, w4, w5, w6, w7};
    u16* ds[8] = {d0, d1, d2, d3, d4, d5, d6, d7};
    W = ws[z]; Wt = ds[z]; K = 1024; N = 1024;
  } else if (z < 12) {
    W = w8; Wt = d8; K = 1024; N = 4096; bx += (z - 8) * 32;
  } else {
    W = w9; Wt = d9; K = 4096; N = 1024; by += (z - 12) * 32;
  }
  __shared__ float tile[32][33];
  const int n0 = bx * 32, k0 = by * 32;
  const int t = threadIdx.x;
  const int r = t >> 3, c4 = (t & 7) * 4;
  float4 v = *(const float4*)&W[(size_t)(k0 + r) * N + n0 + c4];
  tile[r][c4 + 0] = v.x; tile[r][c4 + 1] = v.y;
  tile[r][c4 + 2] = v.z; tile[r][c4 + 3] = v.w;
  __syncthreads();
  ushort4 o;
  o.x = f2bf(tile[c4 + 0][r]);
  o.y = f2bf(tile[c4 + 1][r]);
  o.z = f2bf(tile[c4 + 2][r]);
  o.w = f2bf(tile[c4 + 3][r]);
  *(ushort4*)&Wt[(size_t)(n0 + r) * K + k0 + c4] = o;
}

// =========== 128x128 MFMA GEMM, 2-group/iter pipelined, 64 KiB LDS, 2 blocks/CU ===========
// Round-16: NON-TEMPORAL C stores (global_store nt) — the C write stream (up to
// 98 MB/dispatch) no longer evicts the A/B read panels from the per-XCD L2.
// C consumers read far later (working sets > L2), so nt costs nothing.
// Block decode: 2-level 8x8 super-tiling after the XCD swizzle (r15).
// Sync skeleton FROZEN since r11 (verified).
// ACT: 0 none, 1 relu, 2 relu+1e-6, 3 fused-KVQ (seg n0>>10: V->none, K/Q->relu+1e-6)
template <int ACT, bool BIAS, bool RESID, bool OUTBF, bool SPLITK>
__global__ __launch_bounds__(256, 2) void gemm256(
    const u16* __restrict__ A, const u16* __restrict__ Bt,
    const float* __restrict__ bias, const float* __restrict__ R,
    void* __restrict__ Cout, int M, int N, int K, int lda, int ldb)
{
  __shared__ u16 sh[2][2][128 * 64];   // 64 KiB total
  const int t = threadIdx.x;
  const int wid = t >> 6, lane = t & 63;
  const int wr = wid >> 1, wc = wid & 1;   // 2(M) x 2(N) wave grid
  const int fr = lane & 15, fg = lane >> 4;

  if (SPLITK) {
    const int kp = blockIdx.y;
    A += (size_t)kp * K;
    Bt += (size_t)kp * K;
  }

  int bid = blockIdx.x;
  {
    const int nwg = gridDim.x;
    int q = nwg >> 3, rmd = nwg & 7;
    int xcd = bid & 7, idx = bid >> 3;
    bid = (xcd < rmd ? xcd * (q + 1) : rmd * (q + 1) + (xcd - rmd) * q) + idx;
  }
  const int nxb = N >> 7;
  // 2-level decode: super-tile (8m x 8n blocks) row-major, inner 8x8
  int m0, n0;
  {
    const int nsup = nxb >> 3;
    int sb = bid >> 6;
    int inner = bid & 63;
    int msup = sb / nsup, nsup_i = sb - msup * nsup;
    int ml = inner & 7, nl = inner >> 3;
    m0 = (msup * 8 + ml) * 128;
    n0 = (nsup_i * 8 + nl) * 128;
  }

  auto stageA = [&](int buf, int h, int kt) {
#pragma unroll
    for (int j = 0; j < 2; ++j) {
      int idx = j * 256 + t;
      int r = idx >> 3;
      int gc = ((idx & 7) * 16) ^ ((r & 7) << 4);
      const char* src = (const char*)(A + (size_t)(m0 + h * 64 + r) * lda + kt * 64) + gc;
      char* dst = (char*)&sh[buf][0][0] + h * 8192 + j * 4096 + wid * 1024;
      gload16(src, dst);
    }
  };
  auto stageB = [&](int buf, int h, int kt) {
#pragma unroll
    for (int j = 0; j < 2; ++j) {
      int idx = j * 256 + t;
      int r = idx >> 3;
      int gc = ((idx & 7) * 16) ^ ((r & 7) << 4);
      const char* src = (const char*)(Bt + (size_t)(n0 + h * 64 + r) * ldb + kt * 64) + gc;
      char* dst = (char*)&sh[buf][1][0] + h * 8192 + j * 4096 + wid * 1024;
      gload16(src, dst);
    }
  };
  auto rdA = [&](int buf, int mi, int kk) -> bf16x8 {
    int r = wr * 64 + mi * 16 + fr;
    int c = (kk * 64 + fg * 16) ^ ((r & 7) << 4);
    return *(const bf16x8*)((const char*)&sh[buf][0][0] + r * 128 + c);
  };
  auto rdB = [&](int buf, int ni, int kk) -> bf16x8 {
    int r = wc * 64 + ni * 16 + fr;
    int c = (kk * 64 + fg * 16) ^ ((r & 7) << 4);
    return *(const bf16x8*)((const char*)&sh[buf][1][0] + r * 128 + c);
  };

  f32x4 acc[4][4] = {};

#define MFMA_Q(Q, AF) do {                                                              \
    __builtin_amdgcn_s_setprio(1);                                                      \
    _Pragma("unroll") for (int ni = 0; ni < 4; ++ni) {                                  \
      acc[(Q)][ni] = __builtin_amdgcn_mfma_f32_16x16x32_bf16(AF[0], bfr[ni][0], acc[(Q)][ni], 0, 0, 0); \
      acc[(Q)][ni] = __builtin_amdgcn_mfma_f32_16x16x32_bf16(AF[1], bfr[ni][1], acc[(Q)][ni], 0, 0, 0); } \
    __builtin_amdgcn_s_setprio(0);                                                      \
  } while (0)

#define GROUP(BUF, S1, S2, S3, S4, VC) do {                                             \
    bf16x8 bfr[4][2];                                                                   \
    _Pragma("unroll") for (int ni = 0; ni < 4; ++ni) {                                  \
      bfr[ni][0] = rdB(BUF, ni, 0); bfr[ni][1] = rdB(BUF, ni, 1); }                     \
    bf16x8 A0[2] = {rdA(BUF,0,0), rdA(BUF,0,1)};                                        \
    asm volatile("s_waitcnt lgkmcnt(0)" ::: "memory");                                  \
    __builtin_amdgcn_s_barrier();                                                       \
    S1;                                                                                 \
    bf16x8 A1[2] = {rdA(BUF,1,0), rdA(BUF,1,1)};                                        \
    MFMA_Q(0, A0);                                                                      \
    S2;                                                                                 \
    bf16x8 A2[2] = {rdA(BUF,2,0), rdA(BUF,2,1)};                                        \
    MFMA_Q(1, A1);                                                                      \
    S3;                                                                                 \
    bf16x8 A3[2] = {rdA(BUF,3,0), rdA(BUF,3,1)};                                        \
    MFMA_Q(2, A2);                                                                      \
    S4;                                                                                 \
    MFMA_Q(3, A3);                                                                      \
    if ((VC) == 4) { asm volatile("s_waitcnt vmcnt(4)" ::: "memory"); }                 \
    else if ((VC) == 0) { asm volatile("s_waitcnt vmcnt(0)" ::: "memory"); }            \
    __builtin_amdgcn_s_barrier();                                                       \
  } while (0)

  // prologue: tile0 -> buf0 (A+B), tile1 B -> buf1
  stageA(0, 0, 0); stageA(0, 1, 0);
  stageB(0, 0, 0); stageB(0, 1, 0);
  stageB(1, 0, 1); stageB(1, 1, 1);
  asm volatile("s_waitcnt vmcnt(4)" ::: "memory");
  __builtin_amdgcn_s_barrier();

  const int NIT = K >> 7;  // iterations, 2 K-tiles each
  for (int i = 0; i < NIT - 1; ++i) {
    const int t1 = 2 * i + 1, s0 = 2 * i + 2, s1 = 2 * i + 3;
    GROUP(0, stageA(1, 0, t1), stageA(1, 1, t1), stageB(0, 0, s0), stageB(0, 1, s0), 4);
    GROUP(1, stageA(0, 0, s0), stageA(0, 1, s0), stageB(1, 0, s1), stageB(1, 1, s1), 4);
  }
  {  // tail iteration
    const int t1 = 2 * (NIT - 1) + 1;
    GROUP(0, stageA(1, 0, t1), stageA(1, 1, t1), ((void)0), ((void)0), 0);
    GROUP(1, ((void)0), ((void)0), ((void)0), ((void)0), -1);
  }
#undef GROUP
#undef MFMA_Q

  float* Cf = (float*)Cout;
  if (SPLITK) Cf += (size_t)blockIdx.y * M * N;
  u16* Cb = (u16*)Cout;
  const bool segRelu = (ACT == 3) ? ((n0 >> 10) != 1) : false;
#pragma unroll
  for (int mi = 0; mi < 4; ++mi)
#pragma unroll
    for (int ni = 0; ni < 4; ++ni)
#pragma unroll
      for (int r = 0; r < 4; ++r) {
        int row = m0 + wr * 64 + mi * 16 + fg * 4 + r;
        int col = n0 + wc * 64 + ni * 16 + fr;
        float v = acc[mi][ni][r];
        if (BIAS) v += bias[col];
        if (ACT == 1) v = fmaxf(v, 0.f);
        if (ACT == 2) v = fmaxf(v, 0.f) + 1e-6f;
        if (ACT == 3 && segRelu) v = fmaxf(v, 0.f) + 1e-6f;
        if (RESID) v += R[(size_t)row * N + col];
        if (OUTBF) __builtin_nontemporal_store(f2bf(v), &Cb[(size_t)row * N + col]);
        else       __builtin_nontemporal_store(v,       &Cf[(size_t)row * N + col]);
      }
}

// ---------------- FF-out split-K reduce (FFSK=4 partials) ----------------
__global__ __launch_bounds__(256) void ffred_kernel(
    const float* __restrict__ part, const float* __restrict__ bias,
    const float* __restrict__ R, float* __restrict__ out)
{
  const int idx = blockIdx.x * 256 + threadIdx.x;
  const int c4 = idx & 255;
  float4 s = ((const float4*)R)[idx];
  const float4 bv = ((const float4*)bias)[c4];
  s.x += bv.x; s.y += bv.y; s.z += bv.z; s.w += bv.w;
#pragma unroll
  for (int p = 0; p < FFSK; ++p) {
    float4 v = ((const float4*)part)[(size_t)p * 524288 + idx];
    s.x += v.x; s.y += v.y; s.z += v.z; s.w += v.w;
  }
  ((float4*)out)[idx] = s;
}

// ---------------- 128x128 2-phase MFMA GEMM (small shapes) ----------------
template <int ACT, bool BIAS, bool RESID, bool OUTBF>
__global__ __launch_bounds__(256) void gemm_bf16(
    const u16* __restrict__ A, const u16* __restrict__ Bt,
    const float* __restrict__ bias, const float* __restrict__ R,
    void* __restrict__ Cout, int M, int N, int K)
{
  __shared__ u16 As[2][128 * 32];
  __shared__ u16 Bs[2][128 * 32];
  const int t = threadIdx.x;
  const int m0 = blockIdx.y * 128, n0 = blockIdx.x * 128;
  const int lane = t & 63, wid = t >> 6;
  const int wm = (wid >> 1) * 64, wn = (wid & 1) * 64;
  const int fr = lane & 15, fg = lane >> 4;

  const int srow = t >> 2;
  const int scol = (t & 3) * 8;
  const u16* aptr = A + (size_t)(m0 + srow) * K + scol;
  const u16* bptr = Bt + (size_t)(n0 + srow) * K + scol;
  const size_t rstep = (size_t)64 * K;

  f32x4 acc[4][4] = {};

  auto stage = [&](int c, int k0) {
    gload16(aptr + k0,         &As[c][wid * 512]);
    gload16(aptr + k0 + rstep, &As[c][2048 + wid * 512]);
    gload16(bptr + k0,         &Bs[c][wid * 512]);
    gload16(bptr + k0 + rstep, &Bs[c][2048 + wid * 512]);
  };
  auto compute = [&](int c) {
    bf16x8 af[4], bfr[4];
#pragma unroll
    for (int mi = 0; mi < 4; ++mi)
      af[mi] = *(const bf16x8*)&As[c][(wm + mi * 16 + fr) * 32 + fg * 8];
#pragma unroll
    for (int ni = 0; ni < 4; ++ni)
      bfr[ni] = *(const bf16x8*)&Bs[c][(wn + ni * 16 + fr) * 32 + fg * 8];
#pragma unroll
    for (int mi = 0; mi < 4; ++mi)
#pragma unroll
      for (int ni = 0; ni < 4; ++ni)
        acc[mi][ni] = __builtin_amdgcn_mfma_f32_16x16x32_bf16(af[mi], bfr[ni], acc[mi][ni], 0, 0, 0);
  };

  const int NT = K >> 5;
  stage(0, 0);
  asm volatile("s_waitcnt vmcnt(0)" ::: "memory");
  __builtin_amdgcn_s_barrier();
  int cur = 0;
  for (int kt = 0; kt < NT - 1; ++kt) {
    stage(cur ^ 1, (kt + 1) * 32);
    compute(cur);
    asm volatile("s_waitcnt vmcnt(0)" ::: "memory");
    __builtin_amdgcn_s_barrier();
    cur ^= 1;
  }
  compute(cur);

  float* Cf = (float*)Cout;
  u16* Cb = (u16*)Cout;
#pragma unroll
  for (int mi = 0; mi < 4; ++mi)
#pragma unroll
    for (int ni = 0; ni < 4; ++ni)
#pragma unroll
      for (int r = 0; r < 4; ++r) {
        int row = m0 + wm + mi * 16 + fg * 4 + r;
        int col = n0 + wn + ni * 16 + fr;
        float v = acc[mi][ni][r];
        if (BIAS) v += bias[col];
        if (ACT == 1) v = fmaxf(v, 0.f);
        if (ACT == 2) v = fmaxf(v, 0.f) + 1e-6f;
        if (RESID) v += R[(size_t)row * N + col];
        if (OUTBF) Cb[(size_t)row * N + col] = f2bf(v);
        else       Cf[(size_t)row * N + col] = v;
      }
}

// ---------------- KV state via MFMA over fused buffer (K at col 0, V at col 1024) ----------------
__global__ __launch_bounds__(256) void kv_mfma_kernel(
    const u16* __restrict__ KV, float* __restrict__ kvpart,
    float* __restrict__ kpart, int Ntok, int ld)
{
  const int h = blockIdx.x, b = blockIdx.y, sp = blockIdx.z;
  const int rows = Ntok / NSPLIT;   // 512
  const int nbeg = sp * rows;
  const u16* Kb = KV + ((size_t)b * Ntok + nbeg) * ld + h * DK_;
  const u16* Vb = Kb + 1024;
  __shared__ u16 Kt[64 * 64];
  __shared__ u16 Vt[64 * 64];
  const int t = threadIdx.x;
  const int lane = t & 63, wid = t >> 6;
  const int fr = lane & 15, fg = lane >> 4;
  const int lrow = t >> 2;
  const int lc0 = (t & 3) * 16;

  f32x4 acc[4] = {};
  float kp = 0.f;

  ushort8v ck[2], cv[2];
  {
    const u16* kr = Kb + (size_t)lrow * ld + lc0;
    const u16* vr = Vb + (size_t)lrow * ld + lc0;
    ck[0] = *(const ushort8v*)kr; ck[1] = *(const ushort8v*)(kr + 8);
    cv[0] = *(const ushort8v*)vr; cv[1] = *(const ushort8v*)(vr + 8);
  }
  for (int c = 0; c < rows; c += 64) {
#pragma unroll
    for (int i = 0; i < 2; ++i)
#pragma unroll
      for (int j = 0; j < 8; ++j) kp += bf2f(ck[i][j]);
    __syncthreads();
#pragma unroll
    for (int i = 0; i < 2; ++i)
#pragma unroll
      for (int j = 0; j < 8; ++j) {
        int d = lc0 + i * 8 + j;
        int byteoff = (d * 128 + lrow * 2) ^ ((d & 7) << 4);
        *(u16*)((char*)Kt + byteoff) = ck[i][j];
        *(u16*)((char*)Vt + byteoff) = cv[i][j];
      }
    __syncthreads();
    if (c + 64 < rows) {
      const u16* kr = Kb + (size_t)(c + 64 + lrow) * ld + lc0;
      const u16* vr = Vb + (size_t)(c + 64 + lrow) * ld + lc0;
      ck[0] = *(const ushort8v*)kr; ck[1] = *(const ushort8v*)(kr + 8);
      cv[0] = *(const ushort8v*)vr; cv[1] = *(const ushort8v*)(vr + 8);
    }
#pragma unroll
    for (int ks = 0; ks < 2; ++ks) {
      bf16x8 bv;
      {
        int e = wid * 16 + fr;
        int byteoff = (e * 128 + (ks * 32 + fg * 8) * 2) ^ ((e & 7) << 4);
        bv = *(const bf16x8*)((const char*)Vt + byteoff);
      }
#pragma unroll
      for (int mi = 0; mi < 4; ++mi) {
        int d = mi * 16 + fr;
        int byteoff = (d * 128 + (ks * 32 + fg * 8) * 2) ^ ((d & 7) << 4);
        bf16x8 av = *(const bf16x8*)((const char*)Kt + byteoff);
        acc[mi] = __builtin_amdgcn_mfma_f32_16x16x32_bf16(av, bv, acc[mi], 0, 0, 0);
      }
    }
  }
  float* outp = kvpart + (((size_t)(b * NHEAD + h)) * NSPLIT + sp) * (DK_ * DK_);
#pragma unroll
  for (int mi = 0; mi < 4; ++mi)
#pragma unroll
    for (int r = 0; r < 4; ++r)
      outp[(mi * 16 + fg * 4 + r) * DK_ + wid * 16 + fr] = acc[mi][r];
  for (int off = 32; off >= 1; off >>= 1) kp += __shfl_xor(kp, off);
  __shared__ float kr4[4];
  if (lane == 0) kr4[wid] = kp;
  __syncthreads();
  if (t == 0) kpart[(b * NHEAD + h) * NSPLIT + sp] = kr4[0] + kr4[1] + kr4[2] + kr4[3];
}

// reduce partials -> kv^T bf16 [e][d] + ksum
__global__ __launch_bounds__(256) void kv_reduce_kernel(
    const float* __restrict__ kvpart, const float* __restrict__ kpart,
    u16* __restrict__ kvT, float* __restrict__ ksum)
{
  const int bh = blockIdx.x;
  const int t = threadIdx.x;
  for (int i = t; i < DK_ * DK_; i += 256) {
    int d = i >> 6, e = i & 63;
    float s = 0.f;
#pragma unroll
    for (int p = 0; p < NSPLIT; ++p)
      s += kvpart[((size_t)bh * NSPLIT + p) * (DK_ * DK_) + i];
    kvT[(size_t)bh * (DK_ * DK_) + e * DK_ + d] = f2bf(s);
  }
  if (t == 0) {
    float s = 0.f;
    for (int p = 0; p < NSPLIT; ++p) s += kpart[bh * NSPLIT + p];
    ksum[bh] = s;
  }
}

// ---------------- AO = (Q @ kv) * 1/(qsum*ksum+1e-6) via MFMA; Q row-stride ldq ----------------
__global__ __launch_bounds__(256) void qk_mfma_kernel(
    const u16* __restrict__ Qp, const u16* __restrict__ kvT,
    const float* __restrict__ ksum, u16* __restrict__ AO, int Ntok, int ldq)
{
  const int h = blockIdx.y, b = blockIdx.z;
  const int n0 = blockIdx.x * 128;
  const int t = threadIdx.x;
  const int lane = t & 63, wid = t >> 6;
  const int fr = lane & 15, fg = lane >> 4;

  __shared__ u16 Qs[128 * 64];
  __shared__ u16 KVs[64 * 64];
  __shared__ float qsl[128];

  auto swz = [](int byte, int row) { return byte ^ ((row & 7) << 4); };

  const u16* Qbase = Qp + ((size_t)b * Ntok + n0) * ldq + h * DK_;
#pragma unroll
  for (int j = 0; j < 4; ++j) {
    int id = t + 256 * j;
    int r = id >> 3, cseg = id & 7;
    ushort8v v = *(const ushort8v*)(Qbase + (size_t)r * ldq + cseg * 8);
    *(ushort8v*)((char*)Qs + swz(r * 128 + cseg * 16, r)) = v;
  }
  const u16* Kbase = kvT + ((size_t)(b * NHEAD + h)) * (DK_ * DK_);
#pragma unroll
  for (int j = 0; j < 2; ++j) {
    int id = t + 256 * j;
    int r = id >> 3, cseg = id & 7;
    ushort8v v = *(const ushort8v*)(Kbase + r * DK_ + cseg * 8);
    *(ushort8v*)((char*)KVs + swz(r * 128 + cseg * 16, r)) = v;
  }
  __syncthreads();

  {
    int row = t >> 1, part = t & 1;
    float s = 0.f;
#pragma unroll
    for (int j = 0; j < 4; ++j) {
      bf16x8 v = *(const bf16x8*)((char*)Qs + swz(row * 128 + (part * 4 + j) * 16, row));
#pragma unroll
      for (int i = 0; i < 8; ++i) s += (float)v[i];
    }
    s += __shfl_xor(s, 1);
    if (part == 0) qsl[row] = s;
  }

  const int wm = wid * 32;
  f32x4 acc[2][4] = {};
#pragma unroll
  for (int kk = 0; kk < 2; ++kk) {
    bf16x8 af[2], bfv[4];
#pragma unroll
    for (int mi = 0; mi < 2; ++mi) {
      int row = wm + mi * 16 + fr;
      af[mi] = *(const bf16x8*)((char*)Qs + swz(row * 128 + kk * 64 + fg * 16, row));
    }
#pragma unroll
    for (int ni = 0; ni < 4; ++ni) {
      int row = ni * 16 + fr;
      bfv[ni] = *(const bf16x8*)((char*)KVs + swz(row * 128 + kk * 64 + fg * 16, row));
    }
#pragma unroll
    for (int mi = 0; mi < 2; ++mi)
#pragma unroll
      for (int ni = 0; ni < 4; ++ni)
        acc[mi][ni] = __builtin_amdgcn_mfma_f32_16x16x32_bf16(af[mi], bfv[ni], acc[mi][ni], 0, 0, 0);
  }
  __syncthreads();

  const float ks = ksum[b * NHEAD + h];
  u16* AObase = AO + ((size_t)b * Ntok + n0) * DMODEL + h * DK_;
#pragma unroll
  for (int mi = 0; mi < 2; ++mi)
#pragma unroll
    for (int ni = 0; ni < 4; ++ni)
#pragma unroll
      for (int r = 0; r < 4; ++r) {
        int row = wm + mi * 16 + fg * 4 + r;
        int col = ni * 16 + fr;
        float rn = 1.f / (qsl[row] * ks + 1e-6f);
        AObase[(size_t)row * DMODEL + col] = f2bf(acc[mi][ni][r] * rn);
      }
}

extern "C" void kernel_launch(void* const* d_in, const int* in_sizes, int n_in,
                              void* d_out, int out_size, void* d_ws, size_t ws_size,
                              hipStream_t stream) {
  const float* x     = (const float*)d_in[0];
  const float* lto   = (const float*)d_in[1];
  const float* sa_wq = (const float*)d_in[4];
  const float* sa_wk = (const float*)d_in[5];
  const float* sa_wv = (const float*)d_in[6];
  const float* sa_wo = (const float*)d_in[7];
  const float* ca_wq = (const float*)d_in[8];
  const float* ca_wk = (const float*)d_in[9];
  const float* ca_wv = (const float*)d_in[10];
  const float* ca_wo = (const float*)d_in[11];
  const float* ff_w1 = (const float*)d_in[12];
  const float* ff_b1 = (const float*)d_in[13];
  const float* ff_w2 = (const float*)d_in[14];
  const float* ff_b2 = (const float*)d_in[15];
  const float* ln1_a = (const float*)d_in[16];
  const float* ln1_b = (const float*)d_in[17];
  const float* ln2_a = (const float*)d_in[18];
  const float* ln2_b = (const float*)d_in[19];
  const float* ln3_a = (const float*)d_in[20];
  const float* ln3_b = (const float*)d_in[21];
  float* out = (float*)d_out;

  char* wsb = (char*)d_ws;
  auto take = [&](size_t bytes) {
    char* p = wsb;
    wsb += (bytes + 255) & ~(size_t)255;
    return (void*)p;
  };
  u16* WKVQ = (u16*)take(6291456);   // [3072][1024] concat: sa_wk^T | sa_wv^T | sa_wq^T
  u16* WCKV = (u16*)take(4194304);   // [2048][1024] concat: ca_wk^T | ca_wv^T
  u16* SAOT = (u16*)take(2097152);
  u16* CQT  = (u16*)take(2097152);
  u16* COT  = (u16*)take(2097152);
  u16* FW1T = (u16*)take(8388608);
  u16* FW2T = (u16*)take(8388608);
  u16* R1   = (u16*)take(33554432);   // XN -> AO
  u16* KVQ  = (u16*)take(100663296);  // [16384,3072] QKV out; later [16384,2048] caKV; later FFPART
  u16* R3   = (u16*)take(33554432);   // X1 -> FF hidden bf16
  u16* S1 = (u16*)take(4194304);      // LTON -> FN
  u16* S2 = (u16*)take(4194304);      // CAQ
  u16* S3 = (u16*)take(4194304);      // CAO
  float* LTO1   = (float*)take(8388608);
  float* KVPART = (float*)take(8388608);
  u16*   KVT    = (u16*)take(1048576);
  float* KPART  = (float*)take(2048);
  float* KSUM   = (float*)take(256);
  float* FFPART = (float*)KVQ;        // alias (phase C only; 33.5 MB <= 100.7 MB)

  const int STOK = BATCH * SEQ;   // 16384
  const int LTOK = BATCH * LSEQ;  // 2048
  dim3 blk(256);

  // ---- all weight transpose-converts in ONE launch ----
  wconv_all_kernel<<<dim3(32, 32, 16), blk, 0, stream>>>(
      sa_wk, sa_wv, sa_wq, ca_wk, ca_wv, sa_wo, ca_wq, ca_wo, ff_w1, ff_w2,
      WKVQ, WKVQ + 1048576, WKVQ + 2097152, WCKV, WCKV + 1048576,
      SAOT, CQT, COT, FW1T, FW2T);

  // ---- Phase A: self attention ----
  ln_kernel<<<STOK, blk, 0, stream>>>(x, ln1_a, ln1_b, R1);
  gemm256<3, false, false, true, false><<<dim3(128 * 24), blk, 0, stream>>>(
      R1, WKVQ, nullptr, nullptr, KVQ, STOK, 3072, 1024, 1024, 1024);
  kv_mfma_kernel<<<dim3(NHEAD, BATCH, NSPLIT), blk, 0, stream>>>(KVQ, KVPART, KPART, SEQ, 3072);
  kv_reduce_kernel<<<64, blk, 0, stream>>>(KVPART, KPART, KVT, KSUM);
  qk_mfma_kernel<<<dim3(SEQ / 128, NHEAD, BATCH), blk, 0, stream>>>(KVQ + 2048, KVT, KSUM, R1, SEQ, 3072); // AO -> R1
  gemm256<0, false, true, true, false><<<dim3(128 * 8), blk, 0, stream>>>(
      R1, SAOT, nullptr, x, R3, STOK, 1024, 1024, 1024, 1024);                                             // X1 -> R3

  // ---- Phase B: cross attention ----
  ln_kernel<<<LTOK, blk, 0, stream>>>(lto, ln2_a, ln2_b, S1);
  gemm_bf16<2, false, false, true><<<dim3(8, 16), blk, 0, stream>>>(S1, CQT, nullptr, nullptr, S2, LTOK, 1024, 1024);   // caQ
  gemm256<3, false, false, true, false><<<dim3(128 * 16), blk, 0, stream>>>(
      R3, WCKV, nullptr, nullptr, KVQ, STOK, 2048, 1024, 1024, 1024);
  kv_mfma_kernel<<<dim3(NHEAD, BATCH, NSPLIT), blk, 0, stream>>>(KVQ, KVPART, KPART, SEQ, 2048);
  kv_reduce_kernel<<<64, blk, 0, stream>>>(KVPART, KPART, KVT, KSUM);
  qk_mfma_kernel<<<dim3(LSEQ / 128, NHEAD, BATCH), blk, 0, stream>>>(S2, KVT, KSUM, S3, LSEQ, 1024);        // CAO
  gemm_bf16<0, false, true, false><<<dim3(8, 16), blk, 0, stream>>>(S3, COT, nullptr, lto, LTO1, LTOK, 1024, 1024);     // LTO1 fp32

  // ---- Phase C: feed forward ----
  ln_kernel<<<LTOK, blk, 0, stream>>>(LTO1, ln3_a, ln3_b, S1);
  gemm256<1, true, false, true, false><<<dim3(16 * 32), blk, 0, stream>>>(
      S1, FW1T, ff_b1, nullptr, R3, LTOK, 4096, 1024, 1024, 1024);   // FF hidden direct
  gemm256<0, false, false, false, true><<<dim3(16 * 8, FFSK), blk, 0, stream>>>(
      R3, FW2T, nullptr, nullptr, FFPART, LTOK, 1024, 1024, 4096, 4096);  // FF out partials
  ffred_kernel<<<2048, blk, 0, stream>>>(FFPART, ff_b2, LTO1, out);
}

// Round 17
// 444.961 us; speedup vs baseline: 1.0876x; 1.0876x over previous
//
#include <hip/hip_runtime.h>
#include <hip/hip_bf16.h>

#define BATCH 4
#define SEQ   4096
#define LSEQ  512
#define DMODEL 1024
#define DFF_  4096
#define NHEAD 16
#define DK_   64
#define NSPLIT 8
#define FFSK  4

typedef __attribute__((ext_vector_type(4))) float f32x4;
typedef __attribute__((ext_vector_type(8))) __bf16 bf16x8;
typedef __attribute__((ext_vector_type(8))) unsigned short ushort8v;
typedef unsigned short u16;

__device__ __forceinline__ u16 f2bf(float f) {
  union { float f; unsigned int u; } c; c.f = f;
  unsigned int u = c.u;
  u += 0x7fffu + ((u >> 16) & 1u);
  return (u16)(u >> 16);
}
__device__ __forceinline__ float bf2f(u16 h) {
  union { unsigned int u; float f; } c; c.u = ((unsigned int)h) << 16;
  return c.f;
}
__device__ __forceinline__ void gload16(const void* g, void* l) {
  __builtin_amdgcn_global_load_lds(
      (const __attribute__((address_space(1))) unsigned int*)g,
      (__attribute__((address_space(3))) unsigned int*)l, 16, 0, 0);
}

// ---------------- LayerNorm (ddof=1) -> bf16, float4-vectorized ----------------
__global__ __launch_bounds__(256) void ln_kernel(
    const float* __restrict__ x, const float* __restrict__ alpha,
    const float* __restrict__ beta, u16* __restrict__ y)
{
  const int row = blockIdx.x;
  const int t = threadIdx.x;
  const float4 v = ((const float4*)(x + (size_t)row * DMODEL))[t];
  float s = v.x + v.y + v.z + v.w;
  float ss = v.x * v.x + v.y * v.y + v.z * v.z + v.w * v.w;
  for (int off = 32; off >= 1; off >>= 1) {
    s += __shfl_xor(s, off);
    ss += __shfl_xor(ss, off);
  }
  __shared__ float sbuf[4], ssbuf[4];
  int w = t >> 6;
  if ((t & 63) == 0) { sbuf[w] = s; ssbuf[w] = ss; }
  __syncthreads();
  s = sbuf[0] + sbuf[1] + sbuf[2] + sbuf[3];
  ss = ssbuf[0] + ssbuf[1] + ssbuf[2] + ssbuf[3];
  float mean = s * (1.f / DMODEL);
  float var = (ss - mean * mean * DMODEL) * (1.f / (DMODEL - 1));
  var = fmaxf(var, 0.f);
  float inv = 1.f / (sqrtf(var) + 1e-6f);
  const float4 a = ((const float4*)alpha)[t];
  const float4 bb = ((const float4*)beta)[t];
  ushort4 o;
  o.x = f2bf(a.x * (v.x - mean) * inv + bb.x);
  o.y = f2bf(a.y * (v.y - mean) * inv + bb.y);
  o.z = f2bf(a.z * (v.z - mean) * inv + bb.z);
  o.w = f2bf(a.w * (v.w - mean) * inv + bb.w);
  ((ushort4*)(y + (size_t)row * DMODEL))[t] = o;
}

// ---------------- batched transpose-convert: all 10 weights in ONE launch ----------------
__global__ __launch_bounds__(256) void wconv_all_kernel(
    const float* w0, const float* w1, const float* w2, const float* w3,
    const float* w4, const float* w5, const float* w6, const float* w7,
    const float* w8, const float* w9,
    u16* d0, u16* d1, u16* d2, u16* d3, u16* d4,
    u16* d5, u16* d6, u16* d7, u16* d8, u16* d9)
{
  const int z = blockIdx.z;
  const float* W; u16* Wt; int K, N;
  int bx = blockIdx.x, by = blockIdx.y;
  if (z < 8) {
    const float* ws[8] = {w0, w1, w2, w3, w4, w5, w6, w7};
    u16* ds[8] = {d0, d1, d2, d3, d4, d5, d6, d7};
    W = ws[z]; Wt = ds[z]; K = 1024; N = 1024;
  } else if (z < 12) {
    W = w8; Wt = d8; K = 1024; N = 4096; bx += (z - 8) * 32;
  } else {
    W = w9; Wt = d9; K = 4096; N = 1024; by += (z - 12) * 32;
  }
  __shared__ float tile[32][33];
  const int n0 = bx * 32, k0 = by * 32;
  const int t = threadIdx.x;
  const int r = t >> 3, c4 = (t & 7) * 4;
  float4 v = *(const float4*)&W[(size_t)(k0 + r) * N + n0 + c4];
  tile[r][c4 + 0] = v.x; tile[r][c4 + 1] = v.y;
  tile[r][c4 + 2] = v.z; tile[r][c4 + 3] = v.w;
  __syncthreads();
  ushort4 o;
  o.x = f2bf(tile[c4 + 0][r]);
  o.y = f2bf(tile[c4 + 1][r]);
  o.z = f2bf(tile[c4 + 2][r]);
  o.w = f2bf(tile[c4 + 3][r]);
  *(ushort4*)&Wt[(size_t)(n0 + r) * K + k0 + c4] = o;
}

// =========== 128x128 MFMA GEMM, 2-group/iter pipelined, 64 KiB LDS, 2 blocks/CU ===========
// 2-level 8x8 super-tiling after the XCD swizzle; normal (cached) C stores —
// r16's nt-store experiment doubled WRITE via partial-line HBM writes, reverted.
// Sync skeleton FROZEN since r11 (verified).
// ACT: 0 none, 1 relu, 2 relu+1e-6, 3 fused-KVQ (seg n0>>10: V->none, K/Q->relu+1e-6)
template <int ACT, bool BIAS, bool RESID, bool OUTBF, bool SPLITK>
__global__ __launch_bounds__(256, 2) void gemm256(
    const u16* __restrict__ A, const u16* __restrict__ Bt,
    const float* __restrict__ bias, const float* __restrict__ R,
    void* __restrict__ Cout, int M, int N, int K, int lda, int ldb)
{
  __shared__ u16 sh[2][2][128 * 64];   // 64 KiB total
  const int t = threadIdx.x;
  const int wid = t >> 6, lane = t & 63;
  const int wr = wid >> 1, wc = wid & 1;   // 2(M) x 2(N) wave grid
  const int fr = lane & 15, fg = lane >> 4;

  if (SPLITK) {
    const int kp = blockIdx.y;
    A += (size_t)kp * K;
    Bt += (size_t)kp * K;
  }

  int bid = blockIdx.x;
  {
    const int nwg = gridDim.x;
    int q = nwg >> 3, rmd = nwg & 7;
    int xcd = bid & 7, idx = bid >> 3;
    bid = (xcd < rmd ? xcd * (q + 1) : rmd * (q + 1) + (xcd - rmd) * q) + idx;
  }
  const int nxb = N >> 7;
  // 2-level decode: super-tile (8m x 8n blocks) row-major, inner 8x8
  int m0, n0;
  {
    const int nsup = nxb >> 3;
    int sb = bid >> 6;
    int inner = bid & 63;
    int msup = sb / nsup, nsup_i = sb - msup * nsup;
    int ml = inner & 7, nl = inner >> 3;
    m0 = (msup * 8 + ml) * 128;
    n0 = (nsup_i * 8 + nl) * 128;
  }

  auto stageA = [&](int buf, int h, int kt) {
#pragma unroll
    for (int j = 0; j < 2; ++j) {
      int idx = j * 256 + t;
      int r = idx >> 3;
      int gc = ((idx & 7) * 16) ^ ((r & 7) << 4);
      const char* src = (const char*)(A + (size_t)(m0 + h * 64 + r) * lda + kt * 64) + gc;
      char* dst = (char*)&sh[buf][0][0] + h * 8192 + j * 4096 + wid * 1024;
      gload16(src, dst);
    }
  };
  auto stageB = [&](int buf, int h, int kt) {
#pragma unroll
    for (int j = 0; j < 2; ++j) {
      int idx = j * 256 + t;
      int r = idx >> 3;
      int gc = ((idx & 7) * 16) ^ ((r & 7) << 4);
      const char* src = (const char*)(Bt + (size_t)(n0 + h * 64 + r) * ldb + kt * 64) + gc;
      char* dst = (char*)&sh[buf][1][0] + h * 8192 + j * 4096 + wid * 1024;
      gload16(src, dst);
    }
  };
  auto rdA = [&](int buf, int mi, int kk) -> bf16x8 {
    int r = wr * 64 + mi * 16 + fr;
    int c = (kk * 64 + fg * 16) ^ ((r & 7) << 4);
    return *(const bf16x8*)((const char*)&sh[buf][0][0] + r * 128 + c);
  };
  auto rdB = [&](int buf, int ni, int kk) -> bf16x8 {
    int r = wc * 64 + ni * 16 + fr;
    int c = (kk * 64 + fg * 16) ^ ((r & 7) << 4);
    return *(const bf16x8*)((const char*)&sh[buf][1][0] + r * 128 + c);
  };

  f32x4 acc[4][4] = {};

#define MFMA_Q(Q, AF) do {                                                              \
    __builtin_amdgcn_s_setprio(1);                                                      \
    _Pragma("unroll") for (int ni = 0; ni < 4; ++ni) {                                  \
      acc[(Q)][ni] = __builtin_amdgcn_mfma_f32_16x16x32_bf16(AF[0], bfr[ni][0], acc[(Q)][ni], 0, 0, 0); \
      acc[(Q)][ni] = __builtin_amdgcn_mfma_f32_16x16x32_bf16(AF[1], bfr[ni][1], acc[(Q)][ni], 0, 0, 0); } \
    __builtin_amdgcn_s_setprio(0);                                                      \
  } while (0)

#define GROUP(BUF, S1, S2, S3, S4, VC) do {                                             \
    bf16x8 bfr[4][2];                                                                   \
    _Pragma("unroll") for (int ni = 0; ni < 4; ++ni) {                                  \
      bfr[ni][0] = rdB(BUF, ni, 0); bfr[ni][1] = rdB(BUF, ni, 1); }                     \
    bf16x8 A0[2] = {rdA(BUF,0,0), rdA(BUF,0,1)};                                        \
    asm volatile("s_waitcnt lgkmcnt(0)" ::: "memory");                                  \
    __builtin_amdgcn_s_barrier();                                                       \
    S1;                                                                                 \
    bf16x8 A1[2] = {rdA(BUF,1,0), rdA(BUF,1,1)};                                        \
    MFMA_Q(0, A0);                                                                      \
    S2;                                                                                 \
    bf16x8 A2[2] = {rdA(BUF,2,0), rdA(BUF,2,1)};                                        \
    MFMA_Q(1, A1);                                                                      \
    S3;                                                                                 \
    bf16x8 A3[2] = {rdA(BUF,3,0), rdA(BUF,3,1)};                                        \
    MFMA_Q(2, A2);                                                                      \
    S4;                                                                                 \
    MFMA_Q(3, A3);                                                                      \
    if ((VC) == 4) { asm volatile("s_waitcnt vmcnt(4)" ::: "memory"); }                 \
    else if ((VC) == 0) { asm volatile("s_waitcnt vmcnt(0)" ::: "memory"); }            \
    __builtin_amdgcn_s_barrier();                                                       \
  } while (0)

  // prologue: tile0 -> buf0 (A+B), tile1 B -> buf1
  stageA(0, 0, 0); stageA(0, 1, 0);
  stageB(0, 0, 0); stageB(0, 1, 0);
  stageB(1, 0, 1); stageB(1, 1, 1);
  asm volatile("s_waitcnt vmcnt(4)" ::: "memory");
  __builtin_amdgcn_s_barrier();

  const int NIT = K >> 7;  // iterations, 2 K-tiles each
  for (int i = 0; i < NIT - 1; ++i) {
    const int t1 = 2 * i + 1, s0 = 2 * i + 2, s1 = 2 * i + 3;
    GROUP(0, stageA(1, 0, t1), stageA(1, 1, t1), stageB(0, 0, s0), stageB(0, 1, s0), 4);
    GROUP(1, stageA(0, 0, s0), stageA(0, 1, s0), stageB(1, 0, s1), stageB(1, 1, s1), 4);
  }
  {  // tail iteration
    const int t1 = 2 * (NIT - 1) + 1;
    GROUP(0, stageA(1, 0, t1), stageA(1, 1, t1), ((void)0), ((void)0), 0);
    GROUP(1, ((void)0), ((void)0), ((void)0), ((void)0), -1);
  }
#undef GROUP
#undef MFMA_Q

  float* Cf = (float*)Cout;
  if (SPLITK) Cf += (size_t)blockIdx.y * M * N;
  u16* Cb = (u16*)Cout;
  const bool segRelu = (ACT == 3) ? ((n0 >> 10) != 1) : false;
#pragma unroll
  for (int mi = 0; mi < 4; ++mi)
#pragma unroll
    for (int ni = 0; ni < 4; ++ni)
#pragma unroll
      for (int r = 0; r < 4; ++r) {
        int row = m0 + wr * 64 + mi * 16 + fg * 4 + r;
        int col = n0 + wc * 64 + ni * 16 + fr;
        float v = acc[mi][ni][r];
        if (BIAS) v += bias[col];
        if (ACT == 1) v = fmaxf(v, 0.f);
        if (ACT == 2) v = fmaxf(v, 0.f) + 1e-6f;
        if (ACT == 3 && segRelu) v = fmaxf(v, 0.f) + 1e-6f;
        if (RESID) v += R[(size_t)row * N + col];
        if (OUTBF) Cb[(size_t)row * N + col] = f2bf(v);
        else       Cf[(size_t)row * N + col] = v;
      }
}

// ---------------- FF-out split-K reduce (FFSK=4 partials) ----------------
__global__ __launch_bounds__(256) void ffred_kernel(
    const float* __restrict__ part, const float* __restrict__ bias,
    const float* __restrict__ R, float* __restrict__ out)
{
  const int idx = blockIdx.x * 256 + threadIdx.x;
  const int c4 = idx & 255;
  float4 s = ((const float4*)R)[idx];
  const float4 bv = ((const float4*)bias)[c4];
  s.x += bv.x; s.y += bv.y; s.z += bv.z; s.w += bv.w;
#pragma unroll
  for (int p = 0; p < FFSK; ++p) {
    float4 v = ((const float4*)part)[(size_t)p * 524288 + idx];
    s.x += v.x; s.y += v.y; s.z += v.z; s.w += v.w;
  }
  ((float4*)out)[idx] = s;
}

// ---------------- 128x128 2-phase MFMA GEMM (small shapes) ----------------
template <int ACT, bool BIAS, bool RESID, bool OUTBF>
__global__ __launch_bounds__(256) void gemm_bf16(
    const u16* __restrict__ A, const u16* __restrict__ Bt,
    const float* __restrict__ bias, const float* __restrict__ R,
    void* __restrict__ Cout, int M, int N, int K)
{
  __shared__ u16 As[2][128 * 32];
  __shared__ u16 Bs[2][128 * 32];
  const int t = threadIdx.x;
  const int m0 = blockIdx.y * 128, n0 = blockIdx.x * 128;
  const int lane = t & 63, wid = t >> 6;
  const int wm = (wid >> 1) * 64, wn = (wid & 1) * 64;
  const int fr = lane & 15, fg = lane >> 4;

  const int srow = t >> 2;
  const int scol = (t & 3) * 8;
  const u16* aptr = A + (size_t)(m0 + srow) * K + scol;
  const u16* bptr = Bt + (size_t)(n0 + srow) * K + scol;
  const size_t rstep = (size_t)64 * K;

  f32x4 acc[4][4] = {};

  auto stage = [&](int c, int k0) {
    gload16(aptr + k0,         &As[c][wid * 512]);
    gload16(aptr + k0 + rstep, &As[c][2048 + wid * 512]);
    gload16(bptr + k0,         &Bs[c][wid * 512]);
    gload16(bptr + k0 + rstep, &Bs[c][2048 + wid * 512]);
  };
  auto compute = [&](int c) {
    bf16x8 af[4], bfr[4];
#pragma unroll
    for (int mi = 0; mi < 4; ++mi)
      af[mi] = *(const bf16x8*)&As[c][(wm + mi * 16 + fr) * 32 + fg * 8];
#pragma unroll
    for (int ni = 0; ni < 4; ++ni)
      bfr[ni] = *(const bf16x8*)&Bs[c][(wn + ni * 16 + fr) * 32 + fg * 8];
#pragma unroll
    for (int mi = 0; mi < 4; ++mi)
#pragma unroll
      for (int ni = 0; ni < 4; ++ni)
        acc[mi][ni] = __builtin_amdgcn_mfma_f32_16x16x32_bf16(af[mi], bfr[ni], acc[mi][ni], 0, 0, 0);
  };

  const int NT = K >> 5;
  stage(0, 0);
  asm volatile("s_waitcnt vmcnt(0)" ::: "memory");
  __builtin_amdgcn_s_barrier();
  int cur = 0;
  for (int kt = 0; kt < NT - 1; ++kt) {
    stage(cur ^ 1, (kt + 1) * 32);
    compute(cur);
    asm volatile("s_waitcnt vmcnt(0)" ::: "memory");
    __builtin_amdgcn_s_barrier();
    cur ^= 1;
  }
  compute(cur);

  float* Cf = (float*)Cout;
  u16* Cb = (u16*)Cout;
#pragma unroll
  for (int mi = 0; mi < 4; ++mi)
#pragma unroll
    for (int ni = 0; ni < 4; ++ni)
#pragma unroll
      for (int r = 0; r < 4; ++r) {
        int row = m0 + wm + mi * 16 + fg * 4 + r;
        int col = n0 + wn + ni * 16 + fr;
        float v = acc[mi][ni][r];
        if (BIAS) v += bias[col];
        if (ACT == 1) v = fmaxf(v, 0.f);
        if (ACT == 2) v = fmaxf(v, 0.f) + 1e-6f;
        if (RESID) v += R[(size_t)row * N + col];
        if (OUTBF) Cb[(size_t)row * N + col] = f2bf(v);
        else       Cf[(size_t)row * N + col] = v;
      }
}

// ---------------- KV state via MFMA over fused buffer (K at col 0, V at col 1024) ----------------
__global__ __launch_bounds__(256) void kv_mfma_kernel(
    const u16* __restrict__ KV, float* __restrict__ kvpart,
    float* __restrict__ kpart, int Ntok, int ld)
{
  const int h = blockIdx.x, b = blockIdx.y, sp = blockIdx.z;
  const int rows = Ntok / NSPLIT;   // 512
  const int nbeg = sp * rows;
  const u16* Kb = KV + ((size_t)b * Ntok + nbeg) * ld + h * DK_;
  const u16* Vb = Kb + 1024;
  __shared__ u16 Kt[64 * 64];
  __shared__ u16 Vt[64 * 64];
  const int t = threadIdx.x;
  const int lane = t & 63, wid = t >> 6;
  const int fr = lane & 15, fg = lane >> 4;
  const int lrow = t >> 2;
  const int lc0 = (t & 3) * 16;

  f32x4 acc[4] = {};
  float kp = 0.f;

  ushort8v ck[2], cv[2];
  {
    const u16* kr = Kb + (size_t)lrow * ld + lc0;
    const u16* vr = Vb + (size_t)lrow * ld + lc0;
    ck[0] = *(const ushort8v*)kr; ck[1] = *(const ushort8v*)(kr + 8);
    cv[0] = *(const ushort8v*)vr; cv[1] = *(const ushort8v*)(vr + 8);
  }
  for (int c = 0; c < rows; c += 64) {
#pragma unroll
    for (int i = 0; i < 2; ++i)
#pragma unroll
      for (int j = 0; j < 8; ++j) kp += bf2f(ck[i][j]);
    __syncthreads();
#pragma unroll
    for (int i = 0; i < 2; ++i)
#pragma unroll
      for (int j = 0; j < 8; ++j) {
        int d = lc0 + i * 8 + j;
        int byteoff = (d * 128 + lrow * 2) ^ ((d & 7) << 4);
        *(u16*)((char*)Kt + byteoff) = ck[i][j];
        *(u16*)((char*)Vt + byteoff) = cv[i][j];
      }
    __syncthreads();
    if (c + 64 < rows) {
      const u16* kr = Kb + (size_t)(c + 64 + lrow) * ld + lc0;
      const u16* vr = Vb + (size_t)(c + 64 + lrow) * ld + lc0;
      ck[0] = *(const ushort8v*)kr; ck[1] = *(const ushort8v*)(kr + 8);
      cv[0] = *(const ushort8v*)vr; cv[1] = *(const ushort8v*)(vr + 8);
    }
#pragma unroll
    for (int ks = 0; ks < 2; ++ks) {
      bf16x8 bv;
      {
        int e = wid * 16 + fr;
        int byteoff = (e * 128 + (ks * 32 + fg * 8) * 2) ^ ((e & 7) << 4);
        bv = *(const bf16x8*)((const char*)Vt + byteoff);
      }
#pragma unroll
      for (int mi = 0; mi < 4; ++mi) {
        int d = mi * 16 + fr;
        int byteoff = (d * 128 + (ks * 32 + fg * 8) * 2) ^ ((d & 7) << 4);
        bf16x8 av = *(const bf16x8*)((const char*)Kt + byteoff);
        acc[mi] = __builtin_amdgcn_mfma_f32_16x16x32_bf16(av, bv, acc[mi], 0, 0, 0);
      }
    }
  }
  float* outp = kvpart + (((size_t)(b * NHEAD + h)) * NSPLIT + sp) * (DK_ * DK_);
#pragma unroll
  for (int mi = 0; mi < 4; ++mi)
#pragma unroll
    for (int r = 0; r < 4; ++r)
      outp[(mi * 16 + fg * 4 + r) * DK_ + wid * 16 + fr] = acc[mi][r];
  for (int off = 32; off >= 1; off >>= 1) kp += __shfl_xor(kp, off);
  __shared__ float kr4[4];
  if (lane == 0) kr4[wid] = kp;
  __syncthreads();
  if (t == 0) kpart[(b * NHEAD + h) * NSPLIT + sp] = kr4[0] + kr4[1] + kr4[2] + kr4[3];
}

// reduce partials -> kv^T bf16 [e][d] + ksum
__global__ __launch_bounds__(256) void kv_reduce_kernel(
    const float* __restrict__ kvpart, const float* __restrict__ kpart,
    u16* __restrict__ kvT, float* __restrict__ ksum)
{
  const int bh = blockIdx.x;
  const int t = threadIdx.x;
  for (int i = t; i < DK_ * DK_; i += 256) {
    int d = i >> 6, e = i & 63;
    float s = 0.f;
#pragma unroll
    for (int p = 0; p < NSPLIT; ++p)
      s += kvpart[((size_t)bh * NSPLIT + p) * (DK_ * DK_) + i];
    kvT[(size_t)bh * (DK_ * DK_) + e * DK_ + d] = f2bf(s);
  }
  if (t == 0) {
    float s = 0.f;
    for (int p = 0; p < NSPLIT; ++p) s += kpart[bh * NSPLIT + p];
    ksum[bh] = s;
  }
}

// ---------------- AO = (Q @ kv) * 1/(qsum*ksum+1e-6) via MFMA; Q row-stride ldq ----------------
__global__ __launch_bounds__(256) void qk_mfma_kernel(
    const u16* __restrict__ Qp, const u16* __restrict__ kvT,
    const float* __restrict__ ksum, u16* __restrict__ AO, int Ntok, int ldq)
{
  const int h = blockIdx.y, b = blockIdx.z;
  const int n0 = blockIdx.x * 128;
  const int t = threadIdx.x;
  const int lane = t & 63, wid = t >> 6;
  const int fr = lane & 15, fg = lane >> 4;

  __shared__ u16 Qs[128 * 64];
  __shared__ u16 KVs[64 * 64];
  __shared__ float qsl[128];

  auto swz = [](int byte, int row) { return byte ^ ((row & 7) << 4); };

  const u16* Qbase = Qp + ((size_t)b * Ntok + n0) * ldq + h * DK_;
#pragma unroll
  for (int j = 0; j < 4; ++j) {
    int id = t + 256 * j;
    int r = id >> 3, cseg = id & 7;
    ushort8v v = *(const ushort8v*)(Qbase + (size_t)r * ldq + cseg * 8);
    *(ushort8v*)((char*)Qs + swz(r * 128 + cseg * 16, r)) = v;
  }
  const u16* Kbase = kvT + ((size_t)(b * NHEAD + h)) * (DK_ * DK_);
#pragma unroll
  for (int j = 0; j < 2; ++j) {
    int id = t + 256 * j;
    int r = id >> 3, cseg = id & 7;
    ushort8v v = *(const ushort8v*)(Kbase + r * DK_ + cseg * 8);
    *(ushort8v*)((char*)KVs + swz(r * 128 + cseg * 16, r)) = v;
  }
  __syncthreads();

  {
    int row = t >> 1, part = t & 1;
    float s = 0.f;
#pragma unroll
    for (int j = 0; j < 4; ++j) {
      bf16x8 v = *(const bf16x8*)((char*)Qs + swz(row * 128 + (part * 4 + j) * 16, row));
#pragma unroll
      for (int i = 0; i < 8; ++i) s += (float)v[i];
    }
    s += __shfl_xor(s, 1);
    if (part == 0) qsl[row] = s;
  }

  const int wm = wid * 32;
  f32x4 acc[2][4] = {};
#pragma unroll
  for (int kk = 0; kk < 2; ++kk) {
    bf16x8 af[2], bfv[4];
#pragma unroll
    for (int mi = 0; mi < 2; ++mi) {
      int row = wm + mi * 16 + fr;
      af[mi] = *(const bf16x8*)((char*)Qs + swz(row * 128 + kk * 64 + fg * 16, row));
    }
#pragma unroll
    for (int ni = 0; ni < 4; ++ni) {
      int row = ni * 16 + fr;
      bfv[ni] = *(const bf16x8*)((char*)KVs + swz(row * 128 + kk * 64 + fg * 16, row));
    }
#pragma unroll
    for (int mi = 0; mi < 2; ++mi)
#pragma unroll
      for (int ni = 0; ni < 4; ++ni)
        acc[mi][ni] = __builtin_amdgcn_mfma_f32_16x16x32_bf16(af[mi], bfv[ni], acc[mi][ni], 0, 0, 0);
  }
  __syncthreads();

  const float ks = ksum[b * NHEAD + h];
  u16* AObase = AO + ((size_t)b * Ntok + n0) * DMODEL + h * DK_;
#pragma unroll
  for (int mi = 0; mi < 2; ++mi)
#pragma unroll
    for (int ni = 0; ni < 4; ++ni)
#pragma unroll
      for (int r = 0; r < 4; ++r) {
        int row = wm + mi * 16 + fg * 4 + r;
        int col = ni * 16 + fr;
        float rn = 1.f / (qsl[row] * ks + 1e-6f);
        AObase[(size_t)row * DMODEL + col] = f2bf(acc[mi][ni][r] * rn);
      }
}

extern "C" void kernel_launch(void* const* d_in, const int* in_sizes, int n_in,
                              void* d_out, int out_size, void* d_ws, size_t ws_size,
                              hipStream_t stream) {
  const float* x     = (const float*)d_in[0];
  const float* lto   = (const float*)d_in[1];
  const float* sa_wq = (const float*)d_in[4];
  const float* sa_wk = (const float*)d_in[5];
  const float* sa_wv = (const float*)d_in[6];
  const float* sa_wo = (const float*)d_in[7];
  const float* ca_wq = (const float*)d_in[8];
  const float* ca_wk = (const float*)d_in[9];
  const float* ca_wv = (const float*)d_in[10];
  const float* ca_wo = (const float*)d_in[11];
  const float* ff_w1 = (const float*)d_in[12];
  const float* ff_b1 = (const float*)d_in[13];
  const float* ff_w2 = (const float*)d_in[14];
  const float* ff_b2 = (const float*)d_in[15];
  const float* ln1_a = (const float*)d_in[16];
  const float* ln1_b = (const float*)d_in[17];
  const float* ln2_a = (const float*)d_in[18];
  const float* ln2_b = (const float*)d_in[19];
  const float* ln3_a = (const float*)d_in[20];
  const float* ln3_b = (const float*)d_in[21];
  float* out = (float*)d_out;

  char* wsb = (char*)d_ws;
  auto take = [&](size_t bytes) {
    char* p = wsb;
    wsb += (bytes + 255) & ~(size_t)255;
    return (void*)p;
  };
  u16* WKVQ = (u16*)take(6291456);   // [3072][1024] concat: sa_wk^T | sa_wv^T | sa_wq^T
  u16* WCKV = (u16*)take(4194304);   // [2048][1024] concat: ca_wk^T | ca_wv^T
  u16* SAOT = (u16*)take(2097152);
  u16* CQT  = (u16*)take(2097152);
  u16* COT  = (u16*)take(2097152);
  u16* FW1T = (u16*)take(8388608);
  u16* FW2T = (u16*)take(8388608);
  u16* R1   = (u16*)take(33554432);   // XN -> AO
  u16* KVQ  = (u16*)take(100663296);  // [16384,3072] QKV out; later [16384,2048] caKV; later FFPART
  u16* R3   = (u16*)take(33554432);   // X1 -> FF hidden bf16
  u16* S1 = (u16*)take(4194304);      // LTON -> FN
  u16* S2 = (u16*)take(4194304);      // CAQ
  u16* S3 = (u16*)take(4194304);      // CAO
  float* LTO1   = (float*)take(8388608);
  float* KVPART = (float*)take(8388608);
  u16*   KVT    = (u16*)take(1048576);
  float* KPART  = (float*)take(2048);
  float* KSUM   = (float*)take(256);
  float* FFPART = (float*)KVQ;        // alias (phase C only; 33.5 MB <= 100.7 MB)

  const int STOK = BATCH * SEQ;   // 16384
  const int LTOK = BATCH * LSEQ;  // 2048
  dim3 blk(256);

  // ---- all weight transpose-converts in ONE launch ----
  wconv_all_kernel<<<dim3(32, 32, 16), blk, 0, stream>>>(
      sa_wk, sa_wv, sa_wq, ca_wk, ca_wv, sa_wo, ca_wq, ca_wo, ff_w1, ff_w2,
      WKVQ, WKVQ + 1048576, WKVQ + 2097152, WCKV, WCKV + 1048576,
      SAOT, CQT, COT, FW1T, FW2T);

  // ---- Phase A: self attention ----
  ln_kernel<<<STOK, blk, 0, stream>>>(x, ln1_a, ln1_b, R1);
  gemm256<3, false, false, true, false><<<dim3(128 * 24), blk, 0, stream>>>(
      R1, WKVQ, nullptr, nullptr, KVQ, STOK, 3072, 1024, 1024, 1024);
  kv_mfma_kernel<<<dim3(NHEAD, BATCH, NSPLIT), blk, 0, stream>>>(KVQ, KVPART, KPART, SEQ, 3072);
  kv_reduce_kernel<<<64, blk, 0, stream>>>(KVPART, KPART, KVT, KSUM);
  qk_mfma_kernel<<<dim3(SEQ / 128, NHEAD, BATCH), blk, 0, stream>>>(KVQ + 2048, KVT, KSUM, R1, SEQ, 3072); // AO -> R1
  gemm256<0, false, true, true, false><<<dim3(128 * 8), blk, 0, stream>>>(
      R1, SAOT, nullptr, x, R3, STOK, 1024, 1024, 1024, 1024);                                             // X1 -> R3

  // ---- Phase B: cross attention ----
  ln_kernel<<<LTOK, blk, 0, stream>>>(lto, ln2_a, ln2_b, S1);
  gemm_bf16<2, false, false, true><<<dim3(8, 16), blk, 0, stream>>>(S1, CQT, nullptr, nullptr, S2, LTOK, 1024, 1024);   // caQ
  gemm256<3, false, false, true, false><<<dim3(128 * 16), blk, 0, stream>>>(
      R3, WCKV, nullptr, nullptr, KVQ, STOK, 2048, 1024, 1024, 1024);
  kv_mfma_kernel<<<dim3(NHEAD, BATCH, NSPLIT), blk, 0, stream>>>(KVQ, KVPART, KPART, SEQ, 2048);
  kv_reduce_kernel<<<64, blk, 0, stream>>>(KVPART, KPART, KVT, KSUM);
  qk_mfma_kernel<<<dim3(LSEQ / 128, NHEAD, BATCH), blk, 0, stream>>>(S2, KVT, KSUM, S3, LSEQ, 1024);        // CAO
  gemm_bf16<0, false, true, false><<<dim3(8, 16), blk, 0, stream>>>(S3, COT, nullptr, lto, LTO1, LTOK, 1024, 1024);     // LTO1 fp32

  // ---- Phase C: feed forward ----
  ln_kernel<<<LTOK, blk, 0, stream>>>(LTO1, ln3_a, ln3_b, S1);
  gemm256<1, true, false, true, false><<<dim3(16 * 32), blk, 0, stream>>>(
      S1, FW1T, ff_b1, nullptr, R3, LTOK, 4096, 1024, 1024, 1024);   // FF hidden direct
  gemm256<0, false, false, false, true><<<dim3(16 * 8, FFSK), blk, 0, stream>>>(
      R3, FW2T, nullptr, nullptr, FFPART, LTOK, 1024, 1024, 4096, 4096);  // FF out partials
  ffred_kernel<<<2048, blk, 0, stream>>>(FFPART, ff_b2, LTO1, out);
}

// Round 18
// 418.512 us; speedup vs baseline: 1.1564x; 1.0632x over previous
//
#include <hip/hip_runtime.h>
#include <hip/hip_bf16.h>

#define BATCH 4
#define SEQ   4096
#define LSEQ  512
#define DMODEL 1024
#define DFF_  4096
#define NHEAD 16
#define DK_   64
#define NSPLIT 8
#define FFSK  4

typedef __attribute__((ext_vector_type(4))) float f32x4;
typedef __attribute__((ext_vector_type(8))) __bf16 bf16x8;
typedef __attribute__((ext_vector_type(8))) unsigned short ushort8v;
typedef unsigned short u16;

__device__ __forceinline__ u16 f2bf(float f) {
  union { float f; unsigned int u; } c; c.f = f;
  unsigned int u = c.u;
  u += 0x7fffu + ((u >> 16) & 1u);
  return (u16)(u >> 16);
}
__device__ __forceinline__ float bf2f(u16 h) {
  union { unsigned int u; float f; } c; c.u = ((unsigned int)h) << 16;
  return c.f;
}
__device__ __forceinline__ void gload16(const void* g, void* l) {
  __builtin_amdgcn_global_load_lds(
      (const __attribute__((address_space(1))) unsigned int*)g,
      (__attribute__((address_space(3))) unsigned int*)l, 16, 0, 0);
}

// ---------------- LayerNorm (ddof=1) -> bf16, float4-vectorized ----------------
__global__ __launch_bounds__(256) void ln_kernel(
    const float* __restrict__ x, const float* __restrict__ alpha,
    const float* __restrict__ beta, u16* __restrict__ y)
{
  const int row = blockIdx.x;
  const int t = threadIdx.x;
  const float4 v = ((const float4*)(x + (size_t)row * DMODEL))[t];
  float s = v.x + v.y + v.z + v.w;
  float ss = v.x * v.x + v.y * v.y + v.z * v.z + v.w * v.w;
  for (int off = 32; off >= 1; off >>= 1) {
    s += __shfl_xor(s, off);
    ss += __shfl_xor(ss, off);
  }
  __shared__ float sbuf[4], ssbuf[4];
  int w = t >> 6;
  if ((t & 63) == 0) { sbuf[w] = s; ssbuf[w] = ss; }
  __syncthreads();
  s = sbuf[0] + sbuf[1] + sbuf[2] + sbuf[3];
  ss = ssbuf[0] + ssbuf[1] + ssbuf[2] + ssbuf[3];
  float mean = s * (1.f / DMODEL);
  float var = (ss - mean * mean * DMODEL) * (1.f / (DMODEL - 1));
  var = fmaxf(var, 0.f);
  float inv = 1.f / (sqrtf(var) + 1e-6f);
  const float4 a = ((const float4*)alpha)[t];
  const float4 bb = ((const float4*)beta)[t];
  ushort4 o;
  o.x = f2bf(a.x * (v.x - mean) * inv + bb.x);
  o.y = f2bf(a.y * (v.y - mean) * inv + bb.y);
  o.z = f2bf(a.z * (v.z - mean) * inv + bb.z);
  o.w = f2bf(a.w * (v.w - mean) * inv + bb.w);
  ((ushort4*)(y + (size_t)row * DMODEL))[t] = o;
}

// ---------------- batched transpose-convert: all 10 weights in ONE launch ----------------
__global__ __launch_bounds__(256) void wconv_all_kernel(
    const float* w0, const float* w1, const float* w2, const float* w3,
    const float* w4, const float* w5, const float* w6, const float* w7,
    const float* w8, const float* w9,
    u16* d0, u16* d1, u16* d2, u16* d3, u16* d4,
    u16* d5, u16* d6, u16* d7, u16* d8, u16* d9)
{
  const int z = blockIdx.z;
  const float* W; u16* Wt; int K, N;
  int bx = blockIdx.x, by = blockIdx.y;
  if (z < 8) {
    const float* ws[8] = {w0, w1, w2, w3, w4, w5, w6, w7};
    u16* ds[8] = {d0, d1, d2, d3, d4, d5, d6, d7};
    W = ws[z]; Wt = ds[z]; K = 1024; N = 1024;
  } else if (z < 12) {
    W = w8; Wt = d8; K = 1024; N = 4096; bx += (z - 8) * 32;
  } else {
    W = w9; Wt = d9; K = 4096; N = 1024; by += (z - 12) * 32;
  }
  __shared__ float tile[32][33];
  const int n0 = bx * 32, k0 = by * 32;
  const int t = threadIdx.x;
  const int r = t >> 3, c4 = (t & 7) * 4;
  float4 v = *(const float4*)&W[(size_t)(k0 + r) * N + n0 + c4];
  tile[r][c4 + 0] = v.x; tile[r][c4 + 1] = v.y;
  tile[r][c4 + 2] = v.z; tile[r][c4 + 3] = v.w;
  __syncthreads();
  ushort4 o;
  o.x = f2bf(tile[c4 + 0][r]);
  o.y = f2bf(tile[c4 + 1][r]);
  o.z = f2bf(tile[c4 + 2][r]);
  o.w = f2bf(tile[c4 + 3][r]);
  *(ushort4*)&Wt[(size_t)(n0 + r) * K + k0 + c4] = o;
}

// =========== 128x128 MFMA GEMM, 2-group/iter pipelined, 64 KiB LDS, 2 blocks/CU ===========
// 2-level 8x8 super-tiling after the XCD swizzle; normal (cached) C stores.
// Sync skeleton FROZEN since r11 (verified). r17: now also serves caQ and LTO1.
// ACT: 0 none, 1 relu, 2 relu+1e-6, 3 fused-KVQ (seg n0>>10: V->none, K/Q->relu+1e-6)
template <int ACT, bool BIAS, bool RESID, bool OUTBF, bool SPLITK>
__global__ __launch_bounds__(256, 2) void gemm256(
    const u16* __restrict__ A, const u16* __restrict__ Bt,
    const float* __restrict__ bias, const float* __restrict__ R,
    void* __restrict__ Cout, int M, int N, int K, int lda, int ldb)
{
  __shared__ u16 sh[2][2][128 * 64];   // 64 KiB total
  const int t = threadIdx.x;
  const int wid = t >> 6, lane = t & 63;
  const int wr = wid >> 1, wc = wid & 1;   // 2(M) x 2(N) wave grid
  const int fr = lane & 15, fg = lane >> 4;

  if (SPLITK) {
    const int kp = blockIdx.y;
    A += (size_t)kp * K;
    Bt += (size_t)kp * K;
  }

  int bid = blockIdx.x;
  {
    const int nwg = gridDim.x;
    int q = nwg >> 3, rmd = nwg & 7;
    int xcd = bid & 7, idx = bid >> 3;
    bid = (xcd < rmd ? xcd * (q + 1) : rmd * (q + 1) + (xcd - rmd) * q) + idx;
  }
  const int nxb = N >> 7;
  // 2-level decode: super-tile (8m x 8n blocks) row-major, inner 8x8
  int m0, n0;
  {
    const int nsup = nxb >> 3;
    int sb = bid >> 6;
    int inner = bid & 63;
    int msup = sb / nsup, nsup_i = sb - msup * nsup;
    int ml = inner & 7, nl = inner >> 3;
    m0 = (msup * 8 + ml) * 128;
    n0 = (nsup_i * 8 + nl) * 128;
  }

  auto stageA = [&](int buf, int h, int kt) {
#pragma unroll
    for (int j = 0; j < 2; ++j) {
      int idx = j * 256 + t;
      int r = idx >> 3;
      int gc = ((idx & 7) * 16) ^ ((r & 7) << 4);
      const char* src = (const char*)(A + (size_t)(m0 + h * 64 + r) * lda + kt * 64) + gc;
      char* dst = (char*)&sh[buf][0][0] + h * 8192 + j * 4096 + wid * 1024;
      gload16(src, dst);
    }
  };
  auto stageB = [&](int buf, int h, int kt) {
#pragma unroll
    for (int j = 0; j < 2; ++j) {
      int idx = j * 256 + t;
      int r = idx >> 3;
      int gc = ((idx & 7) * 16) ^ ((r & 7) << 4);
      const char* src = (const char*)(Bt + (size_t)(n0 + h * 64 + r) * ldb + kt * 64) + gc;
      char* dst = (char*)&sh[buf][1][0] + h * 8192 + j * 4096 + wid * 1024;
      gload16(src, dst);
    }
  };
  auto rdA = [&](int buf, int mi, int kk) -> bf16x8 {
    int r = wr * 64 + mi * 16 + fr;
    int c = (kk * 64 + fg * 16) ^ ((r & 7) << 4);
    return *(const bf16x8*)((const char*)&sh[buf][0][0] + r * 128 + c);
  };
  auto rdB = [&](int buf, int ni, int kk) -> bf16x8 {
    int r = wc * 64 + ni * 16 + fr;
    int c = (kk * 64 + fg * 16) ^ ((r & 7) << 4);
    return *(const bf16x8*)((const char*)&sh[buf][1][0] + r * 128 + c);
  };

  f32x4 acc[4][4] = {};

#define MFMA_Q(Q, AF) do {                                                              \
    __builtin_amdgcn_s_setprio(1);                                                      \
    _Pragma("unroll") for (int ni = 0; ni < 4; ++ni) {                                  \
      acc[(Q)][ni] = __builtin_amdgcn_mfma_f32_16x16x32_bf16(AF[0], bfr[ni][0], acc[(Q)][ni], 0, 0, 0); \
      acc[(Q)][ni] = __builtin_amdgcn_mfma_f32_16x16x32_bf16(AF[1], bfr[ni][1], acc[(Q)][ni], 0, 0, 0); } \
    __builtin_amdgcn_s_setprio(0);                                                      \
  } while (0)

#define GROUP(BUF, S1, S2, S3, S4, VC) do {                                             \
    bf16x8 bfr[4][2];                                                                   \
    _Pragma("unroll") for (int ni = 0; ni < 4; ++ni) {                                  \
      bfr[ni][0] = rdB(BUF, ni, 0); bfr[ni][1] = rdB(BUF, ni, 1); }                     \
    bf16x8 A0[2] = {rdA(BUF,0,0), rdA(BUF,0,1)};                                        \
    asm volatile("s_waitcnt lgkmcnt(0)" ::: "memory");                                  \
    __builtin_amdgcn_s_barrier();                                                       \
    S1;                                                                                 \
    bf16x8 A1[2] = {rdA(BUF,1,0), rdA(BUF,1,1)};                                        \
    MFMA_Q(0, A0);                                                                      \
    S2;                                                                                 \
    bf16x8 A2[2] = {rdA(BUF,2,0), rdA(BUF,2,1)};                                        \
    MFMA_Q(1, A1);                                                                      \
    S3;                                                                                 \
    bf16x8 A3[2] = {rdA(BUF,3,0), rdA(BUF,3,1)};                                        \
    MFMA_Q(2, A2);                                                                      \
    S4;                                                                                 \
    MFMA_Q(3, A3);                                                                      \
    if ((VC) == 4) { asm volatile("s_waitcnt vmcnt(4)" ::: "memory"); }                 \
    else if ((VC) == 0) { asm volatile("s_waitcnt vmcnt(0)" ::: "memory"); }            \
    __builtin_amdgcn_s_barrier();                                                       \
  } while (0)

  // prologue: tile0 -> buf0 (A+B), tile1 B -> buf1
  stageA(0, 0, 0); stageA(0, 1, 0);
  stageB(0, 0, 0); stageB(0, 1, 0);
  stageB(1, 0, 1); stageB(1, 1, 1);
  asm volatile("s_waitcnt vmcnt(4)" ::: "memory");
  __builtin_amdgcn_s_barrier();

  const int NIT = K >> 7;  // iterations, 2 K-tiles each
  for (int i = 0; i < NIT - 1; ++i) {
    const int t1 = 2 * i + 1, s0 = 2 * i + 2, s1 = 2 * i + 3;
    GROUP(0, stageA(1, 0, t1), stageA(1, 1, t1), stageB(0, 0, s0), stageB(0, 1, s0), 4);
    GROUP(1, stageA(0, 0, s0), stageA(0, 1, s0), stageB(1, 0, s1), stageB(1, 1, s1), 4);
  }
  {  // tail iteration
    const int t1 = 2 * (NIT - 1) + 1;
    GROUP(0, stageA(1, 0, t1), stageA(1, 1, t1), ((void)0), ((void)0), 0);
    GROUP(1, ((void)0), ((void)0), ((void)0), ((void)0), -1);
  }
#undef GROUP
#undef MFMA_Q

  float* Cf = (float*)Cout;
  if (SPLITK) Cf += (size_t)blockIdx.y * M * N;
  u16* Cb = (u16*)Cout;
  const bool segRelu = (ACT == 3) ? ((n0 >> 10) != 1) : false;
#pragma unroll
  for (int mi = 0; mi < 4; ++mi)
#pragma unroll
    for (int ni = 0; ni < 4; ++ni)
#pragma unroll
      for (int r = 0; r < 4; ++r) {
        int row = m0 + wr * 64 + mi * 16 + fg * 4 + r;
        int col = n0 + wc * 64 + ni * 16 + fr;
        float v = acc[mi][ni][r];
        if (BIAS) v += bias[col];
        if (ACT == 1) v = fmaxf(v, 0.f);
        if (ACT == 2) v = fmaxf(v, 0.f) + 1e-6f;
        if (ACT == 3 && segRelu) v = fmaxf(v, 0.f) + 1e-6f;
        if (RESID) v += R[(size_t)row * N + col];
        if (OUTBF) Cb[(size_t)row * N + col] = f2bf(v);
        else       Cf[(size_t)row * N + col] = v;
      }
}

// ---------------- FF-out split-K reduce (FFSK=4 partials) ----------------
__global__ __launch_bounds__(256) void ffred_kernel(
    const float* __restrict__ part, const float* __restrict__ bias,
    const float* __restrict__ R, float* __restrict__ out)
{
  const int idx = blockIdx.x * 256 + threadIdx.x;
  const int c4 = idx & 255;
  float4 s = ((const float4*)R)[idx];
  const float4 bv = ((const float4*)bias)[c4];
  s.x += bv.x; s.y += bv.y; s.z += bv.z; s.w += bv.w;
#pragma unroll
  for (int p = 0; p < FFSK; ++p) {
    float4 v = ((const float4*)part)[(size_t)p * 524288 + idx];
    s.x += v.x; s.y += v.y; s.z += v.z; s.w += v.w;
  }
  ((float4*)out)[idx] = s;
}

// ---------------- KV state via MFMA over fused buffer (K at col 0, V at col 1024) ----------------
__global__ __launch_bounds__(256) void kv_mfma_kernel(
    const u16* __restrict__ KV, float* __restrict__ kvpart,
    float* __restrict__ kpart, int Ntok, int ld)
{
  const int h = blockIdx.x, b = blockIdx.y, sp = blockIdx.z;
  const int rows = Ntok / NSPLIT;   // 512
  const int nbeg = sp * rows;
  const u16* Kb = KV + ((size_t)b * Ntok + nbeg) * ld + h * DK_;
  const u16* Vb = Kb + 1024;
  __shared__ u16 Kt[64 * 64];
  __shared__ u16 Vt[64 * 64];
  const int t = threadIdx.x;
  const int lane = t & 63, wid = t >> 6;
  const int fr = lane & 15, fg = lane >> 4;
  const int lrow = t >> 2;
  const int lc0 = (t & 3) * 16;

  f32x4 acc[4] = {};
  float kp = 0.f;

  ushort8v ck[2], cv[2];
  {
    const u16* kr = Kb + (size_t)lrow * ld + lc0;
    const u16* vr = Vb + (size_t)lrow * ld + lc0;
    ck[0] = *(const ushort8v*)kr; ck[1] = *(const ushort8v*)(kr + 8);
    cv[0] = *(const ushort8v*)vr; cv[1] = *(const ushort8v*)(vr + 8);
  }
  for (int c = 0; c < rows; c += 64) {
#pragma unroll
    for (int i = 0; i < 2; ++i)
#pragma unroll
      for (int j = 0; j < 8; ++j) kp += bf2f(ck[i][j]);
    __syncthreads();
#pragma unroll
    for (int i = 0; i < 2; ++i)
#pragma unroll
      for (int j = 0; j < 8; ++j) {
        int d = lc0 + i * 8 + j;
        int byteoff = (d * 128 + lrow * 2) ^ ((d & 7) << 4);
        *(u16*)((char*)Kt + byteoff) = ck[i][j];
        *(u16*)((char*)Vt + byteoff) = cv[i][j];
      }
    __syncthreads();
    if (c + 64 < rows) {
      const u16* kr = Kb + (size_t)(c + 64 + lrow) * ld + lc0;
      const u16* vr = Vb + (size_t)(c + 64 + lrow) * ld + lc0;
      ck[0] = *(const ushort8v*)kr; ck[1] = *(const ushort8v*)(kr + 8);
      cv[0] = *(const ushort8v*)vr; cv[1] = *(const ushort8v*)(vr + 8);
    }
#pragma unroll
    for (int ks = 0; ks < 2; ++ks) {
      bf16x8 bv;
      {
        int e = wid * 16 + fr;
        int byteoff = (e * 128 + (ks * 32 + fg * 8) * 2) ^ ((e & 7) << 4);
        bv = *(const bf16x8*)((const char*)Vt + byteoff);
      }
#pragma unroll
      for (int mi = 0; mi < 4; ++mi) {
        int d = mi * 16 + fr;
        int byteoff = (d * 128 + (ks * 32 + fg * 8) * 2) ^ ((d & 7) << 4);
        bf16x8 av = *(const bf16x8*)((const char*)Kt + byteoff);
        acc[mi] = __builtin_amdgcn_mfma_f32_16x16x32_bf16(av, bv, acc[mi], 0, 0, 0);
      }
    }
  }
  float* outp = kvpart + (((size_t)(b * NHEAD + h)) * NSPLIT + sp) * (DK_ * DK_);
#pragma unroll
  for (int mi = 0; mi < 4; ++mi)
#pragma unroll
    for (int r = 0; r < 4; ++r)
      outp[(mi * 16 + fg * 4 + r) * DK_ + wid * 16 + fr] = acc[mi][r];
  for (int off = 32; off >= 1; off >>= 1) kp += __shfl_xor(kp, off);
  __shared__ float kr4[4];
  if (lane == 0) kr4[wid] = kp;
  __syncthreads();
  if (t == 0) kpart[(b * NHEAD + h) * NSPLIT + sp] = kr4[0] + kr4[1] + kr4[2] + kr4[3];
}

// reduce partials -> kv^T bf16 [e][d] + ksum
__global__ __launch_bounds__(256) void kv_reduce_kernel(
    const float* __restrict__ kvpart, const float* __restrict__ kpart,
    u16* __restrict__ kvT, float* __restrict__ ksum)
{
  const int bh = blockIdx.x;
  const int t = threadIdx.x;
  for (int i = t; i < DK_ * DK_; i += 256) {
    int d = i >> 6, e = i & 63;
    float s = 0.f;
#pragma unroll
    for (int p = 0; p < NSPLIT; ++p)
      s += kvpart[((size_t)bh * NSPLIT + p) * (DK_ * DK_) + i];
    kvT[(size_t)bh * (DK_ * DK_) + e * DK_ + d] = f2bf(s);
  }
  if (t == 0) {
    float s = 0.f;
    for (int p = 0; p < NSPLIT; ++p) s += kpart[bh * NSPLIT + p];
    ksum[bh] = s;
  }
}

// ---------------- AO = (Q @ kv) * 1/(qsum*ksum+1e-6) via MFMA; Q row-stride ldq ----------------
__global__ __launch_bounds__(256) void qk_mfma_kernel(
    const u16* __restrict__ Qp, const u16* __restrict__ kvT,
    const float* __restrict__ ksum, u16* __restrict__ AO, int Ntok, int ldq)
{
  const int h = blockIdx.y, b = blockIdx.z;
  const int n0 = blockIdx.x * 128;
  const int t = threadIdx.x;
  const int lane = t & 63, wid = t >> 6;
  const int fr = lane & 15, fg = lane >> 4;

  __shared__ u16 Qs[128 * 64];
  __shared__ u16 KVs[64 * 64];
  __shared__ float qsl[128];

  auto swz = [](int byte, int row) { return byte ^ ((row & 7) << 4); };

  const u16* Qbase = Qp + ((size_t)b * Ntok + n0) * ldq + h * DK_;
#pragma unroll
  for (int j = 0; j < 4; ++j) {
    int id = t + 256 * j;
    int r = id >> 3, cseg = id & 7;
    ushort8v v = *(const ushort8v*)(Qbase + (size_t)r * ldq + cseg * 8);
    *(ushort8v*)((char*)Qs + swz(r * 128 + cseg * 16, r)) = v;
  }
  const u16* Kbase = kvT + ((size_t)(b * NHEAD + h)) * (DK_ * DK_);
#pragma unroll
  for (int j = 0; j < 2; ++j) {
    int id = t + 256 * j;
    int r = id >> 3, cseg = id & 7;
    ushort8v v = *(const ushort8v*)(Kbase + r * DK_ + cseg * 8);
    *(ushort8v*)((char*)KVs + swz(r * 128 + cseg * 16, r)) = v;
  }
  __syncthreads();

  {
    int row = t >> 1, part = t & 1;
    float s = 0.f;
#pragma unroll
    for (int j = 0; j < 4; ++j) {
      bf16x8 v = *(const bf16x8*)((char*)Qs + swz(row * 128 + (part * 4 + j) * 16, row));
#pragma unroll
      for (int i = 0; i < 8; ++i) s += (float)v[i];
    }
    s += __shfl_xor(s, 1);
    if (part == 0) qsl[row] = s;
  }

  const int wm = wid * 32;
  f32x4 acc[2][4] = {};
#pragma unroll
  for (int kk = 0; kk < 2; ++kk) {
    bf16x8 af[2], bfv[4];
#pragma unroll
    for (int mi = 0; mi < 2; ++mi) {
      int row = wm + mi * 16 + fr;
      af[mi] = *(const bf16x8*)((char*)Qs + swz(row * 128 + kk * 64 + fg * 16, row));
    }
#pragma unroll
    for (int ni = 0; ni < 4; ++ni) {
      int row = ni * 16 + fr;
      bfv[ni] = *(const bf16x8*)((char*)KVs + swz(row * 128 + kk * 64 + fg * 16, row));
    }
#pragma unroll
    for (int mi = 0; mi < 2; ++mi)
#pragma unroll
      for (int ni = 0; ni < 4; ++ni)
        acc[mi][ni] = __builtin_amdgcn_mfma_f32_16x16x32_bf16(af[mi], bfv[ni], acc[mi][ni], 0, 0, 0);
  }
  __syncthreads();

  const float ks = ksum[b * NHEAD + h];
  u16* AObase = AO + ((size_t)b * Ntok + n0) * DMODEL + h * DK_;
#pragma unroll
  for (int mi = 0; mi < 2; ++mi)
#pragma unroll
    for (int ni = 0; ni < 4; ++ni)
#pragma unroll
      for (int r = 0; r < 4; ++r) {
        int row = wm + mi * 16 + fg * 4 + r;
        int col = ni * 16 + fr;
        float rn = 1.f / (qsl[row] * ks + 1e-6f);
        AObase[(size_t)row * DMODEL + col] = f2bf(acc[mi][ni][r] * rn);
      }
}

extern "C" void kernel_launch(void* const* d_in, const int* in_sizes, int n_in,
                              void* d_out, int out_size, void* d_ws, size_t ws_size,
                              hipStream_t stream) {
  const float* x     = (const float*)d_in[0];
  const float* lto   = (const float*)d_in[1];
  const float* sa_wq = (const float*)d_in[4];
  const float* sa_wk = (const float*)d_in[5];
  const float* sa_wv = (const float*)d_in[6];
  const float* sa_wo = (const float*)d_in[7];
  const float* ca_wq = (const float*)d_in[8];
  const float* ca_wk = (const float*)d_in[9];
  const float* ca_wv = (const float*)d_in[10];
  const float* ca_wo = (const float*)d_in[11];
  const float* ff_w1 = (const float*)d_in[12];
  const float* ff_b1 = (const float*)d_in[13];
  const float* ff_w2 = (const float*)d_in[14];
  const float* ff_b2 = (const float*)d_in[15];
  const float* ln1_a = (const float*)d_in[16];
  const float* ln1_b = (const float*)d_in[17];
  const float* ln2_a = (const float*)d_in[18];
  const float* ln2_b = (const float*)d_in[19];
  const float* ln3_a = (const float*)d_in[20];
  const float* ln3_b = (const float*)d_in[21];
  float* out = (float*)d_out;

  char* wsb = (char*)d_ws;
  auto take = [&](size_t bytes) {
    char* p = wsb;
    wsb += (bytes + 255) & ~(size_t)255;
    return (void*)p;
  };
  u16* WKVQ = (u16*)take(6291456);   // [3072][1024] concat: sa_wk^T | sa_wv^T | sa_wq^T
  u16* WCKV = (u16*)take(4194304);   // [2048][1024] concat: ca_wk^T | ca_wv^T
  u16* SAOT = (u16*)take(2097152);
  u16* CQT  = (u16*)take(2097152);
  u16* COT  = (u16*)take(2097152);
  u16* FW1T = (u16*)take(8388608);
  u16* FW2T = (u16*)take(8388608);
  u16* R1   = (u16*)take(33554432);   // XN -> AO
  u16* KVQ  = (u16*)take(100663296);  // [16384,3072] QKV out; later [16384,2048] caKV; later FFPART
  u16* R3   = (u16*)take(33554432);   // X1 -> FF hidden bf16
  u16* S1 = (u16*)take(4194304);      // LTON -> FN
  u16* S2 = (u16*)take(4194304);      // CAQ
  u16* S3 = (u16*)take(4194304);      // CAO
  float* LTO1   = (float*)take(8388608);
  float* KVPART = (float*)take(8388608);
  u16*   KVT    = (u16*)take(1048576);
  float* KPART  = (float*)take(2048);
  float* KSUM   = (float*)take(256);
  float* FFPART = (float*)KVQ;        // alias (phase C only; 33.5 MB <= 100.7 MB)

  const int STOK = BATCH * SEQ;   // 16384
  const int LTOK = BATCH * LSEQ;  // 2048
  dim3 blk(256);

  // ---- all weight transpose-converts in ONE launch ----
  wconv_all_kernel<<<dim3(32, 32, 16), blk, 0, stream>>>(
      sa_wk, sa_wv, sa_wq, ca_wk, ca_wv, sa_wo, ca_wq, ca_wo, ff_w1, ff_w2,
      WKVQ, WKVQ + 1048576, WKVQ + 2097152, WCKV, WCKV + 1048576,
      SAOT, CQT, COT, FW1T, FW2T);

  // ---- Phase A: self attention ----
  ln_kernel<<<STOK, blk, 0, stream>>>(x, ln1_a, ln1_b, R1);
  gemm256<3, false, false, true, false><<<dim3(128 * 24), blk, 0, stream>>>(
      R1, WKVQ, nullptr, nullptr, KVQ, STOK, 3072, 1024, 1024, 1024);
  kv_mfma_kernel<<<dim3(NHEAD, BATCH, NSPLIT), blk, 0, stream>>>(KVQ, KVPART, KPART, SEQ, 3072);
  kv_reduce_kernel<<<64, blk, 0, stream>>>(KVPART, KPART, KVT, KSUM);
  qk_mfma_kernel<<<dim3(SEQ / 128, NHEAD, BATCH), blk, 0, stream>>>(KVQ + 2048, KVT, KSUM, R1, SEQ, 3072); // AO -> R1
  gemm256<0, false, true, true, false><<<dim3(128 * 8), blk, 0, stream>>>(
      R1, SAOT, nullptr, x, R3, STOK, 1024, 1024, 1024, 1024);                                             // X1 -> R3

  // ---- Phase B: cross attention ----
  ln_kernel<<<LTOK, blk, 0, stream>>>(lto, ln2_a, ln2_b, S1);
  gemm256<2, false, false, true, false><<<dim3(16 * 8), blk, 0, stream>>>(
      S1, CQT, nullptr, nullptr, S2, LTOK, 1024, 1024, 1024, 1024);                                        // caQ
  gemm256<3, false, false, true, false><<<dim3(128 * 16), blk, 0, stream>>>(
      R3, WCKV, nullptr, nullptr, KVQ, STOK, 2048, 1024, 1024, 1024);
  kv_mfma_kernel<<<dim3(NHEAD, BATCH, NSPLIT), blk, 0, stream>>>(KVQ, KVPART, KPART, SEQ, 2048);
  kv_reduce_kernel<<<64, blk, 0, stream>>>(KVPART, KPART, KVT, KSUM);
  qk_mfma_kernel<<<dim3(LSEQ / 128, NHEAD, BATCH), blk, 0, stream>>>(S2, KVT, KSUM, S3, LSEQ, 1024);        // CAO
  gemm256<0, false, true, false, false><<<dim3(16 * 8), blk, 0, stream>>>(
      S3, COT, nullptr, lto, LTO1, LTOK, 1024, 1024, 1024, 1024);                                          // LTO1 fp32

  // ---- Phase C: feed forward ----
  ln_kernel<<<LTOK, blk, 0, stream>>>(LTO1, ln3_a, ln3_b, S1);
  gemm256<1, true, false, true, false><<<dim3(16 * 32), blk, 0, stream>>>(
      S1, FW1T, ff_b1, nullptr, R3, LTOK, 4096, 1024, 1024, 1024);   // FF hidden direct
  gemm256<0, false, false, false, true><<<dim3(16 * 8, FFSK), blk, 0, stream>>>(
      R3, FW2T, nullptr, nullptr, FFPART, LTOK, 1024, 1024, 4096, 4096);  // FF out partials
  ffred_kernel<<<2048, blk, 0, stream>>>(FFPART, ff_b2, LTO1, out);
}